// Round 1
// baseline (1099.664 us; speedup 1.0000x reference)
//
#include <hip/hip_runtime.h>

typedef unsigned short ushort_t;
typedef __attribute__((ext_vector_type(8))) short bf16x8;
typedef __attribute__((ext_vector_type(4))) float f32x4;

__device__ __forceinline__ unsigned short f2bf(float f) {
  unsigned int u = __float_as_uint(f);
  u += 0x7fffu + ((u >> 16) & 1u);
  return (unsigned short)(u >> 16);
}

__device__ __forceinline__ f32x4 mfma16(bf16x8 a, bf16x8 b, f32x4 c) {
  return __builtin_amdgcn_mfma_f32_16x16x32_bf16(a, b, c, 0, 0, 0);
}

// ---------------- elementwise f32 -> bf16 convert ----------------
__global__ void cvt_bf16_kernel(const float* __restrict__ src,
                                ushort_t* __restrict__ dst, int n) {
  int i = blockIdx.x * 256 + threadIdx.x;
  if (i < n) dst[i] = f2bf(src[i]);
}

// ---------------- generic C = scale*(A @ B^T) + bias ----------------
// A: rows x K bf16 (row-major, lda), B: cols x K bf16 (row-major, ldb).
// Per-wave 16x16 tile; block = 4 waves stacked along rows (64 rows x 16 cols).
// z decomposes as (b = z>>4, g = z&15); per-(b,g) base offsets via strides.
__global__ __launch_bounds__(256) void gemm_bt(
    const ushort_t* __restrict__ A, const ushort_t* __restrict__ B,
    void* __restrict__ Cv, const float* __restrict__ bias,
    int lda, int ldb, int ldc,
    long sAb, long sAg, long sBb, long sBg, long sCb, long sCg,
    int K, float scale, int c_bf16) {
  int wave = threadIdx.x >> 6, lane = threadIdx.x & 63;
  int la = lane & 15, qd = lane >> 4;
  int z = blockIdx.z, b = z >> 4, g = z & 15;
  const ushort_t* Az = A + (long)b * sAb + (long)g * sAg;
  const ushort_t* Bz = B + (long)b * sBb + (long)g * sBg;
  int row0 = blockIdx.y * 64 + wave * 16;
  int col0 = blockIdx.x * 16;
  const ushort_t* ar = Az + (long)(row0 + la) * lda + qd * 8;
  const ushort_t* br = Bz + (long)(col0 + la) * ldb + qd * 8;
  f32x4 acc = {0.f, 0.f, 0.f, 0.f};
  for (int k = 0; k < K; k += 32) {
    bf16x8 av = *(const bf16x8*)(ar + k);
    bf16x8 bv = *(const bf16x8*)(br + k);
    acc = mfma16(av, bv, acc);
  }
  int crow = row0 + qd * 4, ccol = col0 + la;
  float bb = bias ? bias[ccol] : 0.f;
  long cbase = (long)b * sCb + (long)g * sCg;
#pragma unroll
  for (int j = 0; j < 4; ++j) {
    float v = acc[j] * scale + bb;
    long addr = cbase + (long)(crow + j) * ldc + ccol;
    if (c_bf16) ((ushort_t*)Cv)[addr] = f2bf(v);
    else ((float*)Cv)[addr] = v;
  }
}

// ---------------- S[b,n,g,m] += log(max(pe . pos_w_g + pos_b_g, eps)) ------
// Computed transposed: C'[g][pe_row], A = pos_w (16x64 bf16, preloaded frags),
// B = pe rows (fp32, inline-converted). One wave per 16 pe-rows.
__global__ __launch_bounds__(256) void pe_bias_kernel(
    const float* __restrict__ pe, const ushort_t* __restrict__ poswb,
    const float* __restrict__ pos_b, float* __restrict__ S) {
  int wave = threadIdx.x >> 6, lane = threadIdx.x & 63;
  int la = lane & 15, qd = lane >> 4;
  long r0 = ((long)blockIdx.x * 4 + wave) * 16;  // pe-row tile base
  const ushort_t* ar = poswb + la * 64 + qd * 8;
  bf16x8 a0 = *(const bf16x8*)(ar);
  bf16x8 a1 = *(const bf16x8*)(ar + 32);
  long r = r0 + la;
  const float* prow = pe + r * 64 + qd * 8;
  f32x4 f0 = *(const f32x4*)(prow);
  f32x4 f1 = *(const f32x4*)(prow + 4);
  f32x4 f2 = *(const f32x4*)(prow + 32);
  f32x4 f3 = *(const f32x4*)(prow + 36);
  bf16x8 b0, b1;
#pragma unroll
  for (int j = 0; j < 4; ++j) {
    b0[j] = (short)f2bf(f0[j]); b0[j + 4] = (short)f2bf(f1[j]);
    b1[j] = (short)f2bf(f2[j]); b1[j + 4] = (short)f2bf(f3[j]);
  }
  f32x4 acc = {0.f, 0.f, 0.f, 0.f};
  acc = mfma16(a0, b0, acc);
  acc = mfma16(a1, b1, acc);
  // epilogue: C' row = g = qd*4+j, col = pe-row r0+la
  long rr = r0 + la;                       // (b*1024+n)*1024 + m
  long sbase = (rr >> 10) * 16384 + (rr & 1023);
#pragma unroll
  for (int j = 0; j < 4; ++j) {
    int g = qd * 4 + j;
    float w = __logf(fmaxf(acc[j] + pos_b[g], 1e-6f));
    long addr = sbase + (long)g * 1024;
    S[addr] += w;
  }
}

// ---------------- per-row softmax stats: max and 1/sum(exp) ----------------
__global__ __launch_bounds__(256) void row_stats_kernel(
    const float* __restrict__ S, float* __restrict__ Mx,
    float* __restrict__ invL) {
  int wave = threadIdx.x >> 6, lane = threadIdx.x & 63;
  int rr = blockIdx.x * 4 + wave;  // 0..32767
  const float* row = S + (long)rr * 1024;
  float mx = -3.0e38f, sm = 0.f;
#pragma unroll
  for (int i = 0; i < 16; ++i) {
    float v = row[lane + i * 64];
    if (v > mx) { sm *= __expf(mx - v); mx = v; }
    sm += __expf(v - mx);
  }
  for (int off = 32; off >= 1; off >>= 1) {
    float omx = __shfl_xor(mx, off);
    float osm = __shfl_xor(sm, off);
    float nmx = fmaxf(mx, omx);
    sm = sm * __expf(mx - nmx) + osm * __expf(omx - nmx);
    mx = nmx;
  }
  if (lane == 0) { Mx[rr] = mx; invL[rr] = 1.0f / sm; }
}

// ---------------- out = softmax(S) @ V2T^T + conv_b ----------------
// A-frag built inline: p = exp(s - mx) * invL, converted to bf16.
// Block = 4 waves along cols (covers all 64 output cols of the group).
__global__ __launch_bounds__(256) void out_gemm_kernel(
    const float* __restrict__ S, const float* __restrict__ Mx,
    const float* __restrict__ invL, const ushort_t* __restrict__ V2T,
    const float* __restrict__ conv_b, float* __restrict__ out) {
  int wave = threadIdx.x >> 6, lane = threadIdx.x & 63;
  int la = lane & 15, qd = lane >> 4;
  int z = blockIdx.z, b = z >> 4, g = z & 15;
  int row0 = blockIdx.y * 16;   // n tile
  int col0 = wave * 16;         // o tile within 64
  const float* Az = S + (long)b * 16777216 + (long)g * 1024;
  const ushort_t* Bz = V2T + (long)z * 65536;
  int an = row0 + la;
  const float* arow = Az + (long)an * 16384 + qd * 8;
  int rr = (b * 1024 + an) * 16 + g;
  float mx = Mx[rr], il = invL[rr];
  const ushort_t* brow = Bz + (long)(col0 + la) * 1024 + qd * 8;
  f32x4 acc = {0.f, 0.f, 0.f, 0.f};
  for (int k = 0; k < 1024; k += 32) {
    f32x4 f0 = *(const f32x4*)(arow + k);
    f32x4 f1 = *(const f32x4*)(arow + k + 4);
    bf16x8 av;
#pragma unroll
    for (int j = 0; j < 4; ++j) {
      av[j]     = (short)f2bf(__expf(f0[j] - mx) * il);
      av[j + 4] = (short)f2bf(__expf(f1[j] - mx) * il);
    }
    bf16x8 bv = *(const bf16x8*)(brow + k);
    acc = mfma16(av, bv, acc);
  }
  int crow = row0 + qd * 4, ccol = col0 + la;
  float cb = conv_b[g * 64 + ccol];
#pragma unroll
  for (int j = 0; j < 4; ++j) {
    out[(long)b * 1048576 + (long)(crow + j) * 1024 + g * 64 + ccol] =
        acc[j] + cb;
  }
}

extern "C" void kernel_launch(void* const* d_in, const int* in_sizes, int n_in,
                              void* d_out, int out_size, void* d_ws, size_t ws_size,
                              hipStream_t stream) {
  const float* roi_feat = (const float*)d_in[0];   // (2,1024,1024)
  const float* pe       = (const float*)d_in[1];   // (2,1024,1024,64)
  const float* pos_w    = (const float*)d_in[2];   // (16,64)
  const float* pos_b    = (const float*)d_in[3];   // (16)
  const float* q_w      = (const float*)d_in[4];   // (1024,1024)
  const float* q_b      = (const float*)d_in[5];   // (1024)
  const float* k_w      = (const float*)d_in[6];
  const float* k_b      = (const float*)d_in[7];
  const float* conv_w   = (const float*)d_in[8];
  const float* conv_b   = (const float*)d_in[9];
  float* out = (float*)d_out;

  char* w = (char*)d_ws;
  ushort_t* rfb   = (ushort_t*)w; w += (size_t)4 << 20;   // 2M bf16
  ushort_t* qwb   = (ushort_t*)w; w += (size_t)2 << 20;
  ushort_t* kwb   = (ushort_t*)w; w += (size_t)2 << 20;
  ushort_t* cwb   = (ushort_t*)w; w += (size_t)2 << 20;
  ushort_t* poswb = (ushort_t*)w; w += (size_t)1 << 12;
  ushort_t* Qb    = (ushort_t*)w; w += (size_t)4 << 20;   // 2048x1024 bf16
  ushort_t* Kb    = (ushort_t*)w; w += (size_t)4 << 20;
  ushort_t* V2T   = (ushort_t*)w; w += (size_t)4 << 20;   // 32 x (64x1024) bf16
  float*    Mx    = (float*)w;    w += (size_t)1 << 17;
  float*    invL  = (float*)w;    w += (size_t)1 << 17;
  float*    S     = (float*)w;    w += (size_t)134217728; // (2,1024,16,1024) f32

  // converts
  cvt_bf16_kernel<<<8192, 256, 0, stream>>>(roi_feat, rfb, 2097152);
  cvt_bf16_kernel<<<4096, 256, 0, stream>>>(q_w, qwb, 1048576);
  cvt_bf16_kernel<<<4096, 256, 0, stream>>>(k_w, kwb, 1048576);
  cvt_bf16_kernel<<<4096, 256, 0, stream>>>(conv_w, cwb, 1048576);
  cvt_bf16_kernel<<<4, 256, 0, stream>>>(pos_w, poswb, 1024);

  // Q = roi @ q_w^T + q_b  (bf16 out), rows = b*1024+n (2048), cols = qidx
  gemm_bt<<<dim3(64, 32, 1), 256, 0, stream>>>(
      rfb, qwb, Qb, q_b, 1024, 1024, 1024, 0, 0, 0, 0, 0, 0, 1024, 1.f, 1);
  // K
  gemm_bt<<<dim3(64, 32, 1), 256, 0, stream>>>(
      rfb, kwb, Kb, k_b, 1024, 1024, 1024, 0, 0, 0, 0, 0, 0, 1024, 1.f, 1);
  // V2T[b,g][o][m] = sum_f cw[g*64+o][f] * roi[b][m][f]  (bf16 out)
  gemm_bt<<<dim3(64, 1, 32), 256, 0, stream>>>(
      cwb, rfb, V2T, (const float*)nullptr, 1024, 1024, 1024,
      0, 65536, 1048576, 0, 1048576, 65536, 1024, 1.f, 1);
  // S[b,n,g,m] = (Q_g . K_g) / 8  (f32)
  gemm_bt<<<dim3(64, 16, 32), 256, 0, stream>>>(
      Qb, Kb, S, (const float*)nullptr, 1024, 1024, 16384,
      1048576, 64, 1048576, 64, 16777216, 1024, 64, 0.125f, 0);
  // S += log(max(pe . pos_w + pos_b, 1e-6))
  pe_bias_kernel<<<32768, 256, 0, stream>>>(pe, poswb, pos_b, S);
  // softmax stats
  row_stats_kernel<<<8192, 256, 0, stream>>>(S, Mx, invL);
  // out = softmax(S) @ V2T^T + conv_b
  out_gemm_kernel<<<dim3(1, 64, 32), 256, 0, stream>>>(
      S, Mx, invL, V2T, conv_b, out);
}

// Round 2
// 1008.087 us; speedup vs baseline: 1.0908x; 1.0908x over previous
//
#include <hip/hip_runtime.h>

typedef unsigned short ushort_t;
typedef __attribute__((ext_vector_type(8))) short bf16x8;
typedef __attribute__((ext_vector_type(4))) float f32x4;

__device__ __forceinline__ unsigned short f2bf(float f) {
  unsigned int u = __float_as_uint(f);
  u += 0x7fffu + ((u >> 16) & 1u);
  return (unsigned short)(u >> 16);
}

__device__ __forceinline__ f32x4 mfma16(bf16x8 a, bf16x8 b, f32x4 c) {
  return __builtin_amdgcn_mfma_f32_16x16x32_bf16(a, b, c, 0, 0, 0);
}

// ---------------- elementwise f32 -> bf16 convert ----------------
__global__ void cvt_bf16_kernel(const float* __restrict__ src,
                                ushort_t* __restrict__ dst, int n) {
  int i = blockIdx.x * 256 + threadIdx.x;
  if (i < n) dst[i] = f2bf(src[i]);
}

// ---------------- generic C = scale*(A @ B^T) + bias (bf16 out) -----------
__global__ __launch_bounds__(256) void gemm_bt(
    const ushort_t* __restrict__ A, const ushort_t* __restrict__ B,
    void* __restrict__ Cv, const float* __restrict__ bias,
    int lda, int ldb, int ldc,
    long sAb, long sAg, long sBb, long sBg, long sCb, long sCg,
    int K, float scale, int c_bf16) {
  int wave = threadIdx.x >> 6, lane = threadIdx.x & 63;
  int la = lane & 15, qd = lane >> 4;
  int z = blockIdx.z, b = z >> 4, g = z & 15;
  const ushort_t* Az = A + (long)b * sAb + (long)g * sAg;
  const ushort_t* Bz = B + (long)b * sBb + (long)g * sBg;
  int row0 = blockIdx.y * 64 + wave * 16;
  int col0 = blockIdx.x * 16;
  const ushort_t* ar = Az + (long)(row0 + la) * lda + qd * 8;
  const ushort_t* br = Bz + (long)(col0 + la) * ldb + qd * 8;
  f32x4 acc = {0.f, 0.f, 0.f, 0.f};
  for (int k = 0; k < K; k += 32) {
    bf16x8 av = *(const bf16x8*)(ar + k);
    bf16x8 bv = *(const bf16x8*)(br + k);
    acc = mfma16(av, bv, acc);
  }
  int crow = row0 + qd * 4, ccol = col0 + la;
  float bb = bias ? bias[ccol] : 0.f;
  long cbase = (long)b * sCb + (long)g * sCg;
#pragma unroll
  for (int j = 0; j < 4; ++j) {
    float v = acc[j] * scale + bb;
    long addr = cbase + (long)(crow + j) * ldc + ccol;
    if (c_bf16) ((ushort_t*)Cv)[addr] = f2bf(v);
    else ((float*)Cv)[addr] = v;
  }
}

// ---------------- fused flash attention over the S path ----------------
// Block: 1024 threads = 16 waves, wave = group g. One block per (b, 8 n-rows).
// Loop m in steps of 32: stage pe->LDS bf16, W = log(max(pe.pos_w+pos_b,eps))
// via MFMA into LDS f32, S = QK^T/8 + W via MFMA, online softmax, P->LDS
// transpose (wave-local), PV against V2T.
__global__ __launch_bounds__(1024, 4) void flash_kernel(
    const float* __restrict__ pe, const ushort_t* __restrict__ poswb,
    const float* __restrict__ pos_b, const ushort_t* __restrict__ Qb,
    const ushort_t* __restrict__ Kb, const ushort_t* __restrict__ V2T,
    const float* __restrict__ conv_b, float* __restrict__ out) {
  __shared__ ushort_t peb[256 * 72];      // [nm=n_l*32+m_l][72 (pad)] bf16
  __shared__ float    wlog[256 * 17];     // [nm][17 (pad)] f32
  __shared__ ushort_t ptrb[16][8 * 32];   // per-wave P^T buffer [row][32]

  int tid = threadIdx.x;
  int wave = tid >> 6, lane = tid & 63;
  int la = lane & 15, qd = lane >> 4;
  int g = wave;
  int bx = blockIdx.x;
  int b = bx & 1, nt = bx >> 1;     // b per XCD parity: L2 holds one batch
  int n0 = nt * 8;

  // q A-frags (rows la: n = n0 + (la&7), duplicated for la>=8)
  const ushort_t* qptr =
      Qb + (((long)(b * 1024 + n0 + (la & 7))) << 10) + g * 64 + qd * 8;
  bf16x8 aq0 = *(const bf16x8*)qptr;
  bf16x8 aq1 = *(const bf16x8*)(qptr + 32);
  // pos_w B-frags (rows = g = la)
  const ushort_t* pwp = poswb + la * 64 + qd * 8;
  bf16x8 pw0 = *(const bf16x8*)pwp;
  bf16x8 pw1 = *(const bf16x8*)(pwp + 32);
  float pb_la = pos_b[la];

  // pe staging indices: each lane loads 16 f32 (one n-row chunk of 8KB per
  // 128 lanes), writes 16 bf16 to peb.
  int n_l = tid >> 7, rr = tid & 127;
  int m_l = rr >> 2, e0 = (rr & 3) * 16;
  const float* psrc =
      pe + (((long)(b * 1024 + n0 + n_l) << 10) + m_l) * 64 + e0;
  int pebidx = (n_l * 32 + m_l) * 72 + e0;

  f32x4 O0 = {0,0,0,0}, O1 = {0,0,0,0}, O2 = {0,0,0,0}, O3 = {0,0,0,0};
  float m_i[4], l_i[4];
#pragma unroll
  for (int j = 0; j < 4; ++j) { m_i[j] = -1e30f; l_i[j] = 0.f; }

  f32x4 p0 = *(const f32x4*)(psrc);
  f32x4 p1 = *(const f32x4*)(psrc + 4);
  f32x4 p2 = *(const f32x4*)(psrc + 8);
  f32x4 p3 = *(const f32x4*)(psrc + 12);

  for (int t = 0; t < 32; ++t) {
    // ---- stage pe tile (bf16) ----
    bf16x8 c0, c1;
#pragma unroll
    for (int j = 0; j < 4; ++j) {
      c0[j] = (short)f2bf(p0[j]); c0[j + 4] = (short)f2bf(p1[j]);
      c1[j] = (short)f2bf(p2[j]); c1[j + 4] = (short)f2bf(p3[j]);
    }
    *(bf16x8*)&peb[pebidx] = c0;
    *(bf16x8*)&peb[pebidx + 8] = c1;
    __syncthreads();                       // bar1: peb ready
    if (t < 31) {                          // prefetch next pe tile
      const float* ps = psrc + (t + 1) * 2048;
      p0 = *(const f32x4*)(ps);
      p1 = *(const f32x4*)(ps + 4);
      p2 = *(const f32x4*)(ps + 8);
      p3 = *(const f32x4*)(ps + 12);
    }
    // ---- W-GEMM: 256 (n,m)-rows x 16 g, wave w does rows w*16..+15 ----
    const ushort_t* pa = &peb[(wave * 16 + la) * 72 + qd * 8];
    bf16x8 wa0 = *(const bf16x8*)pa;
    bf16x8 wa1 = *(const bf16x8*)(pa + 32);
    f32x4 wacc = {0.f, 0.f, 0.f, 0.f};
    wacc = mfma16(wa0, pw0, wacc);
    wacc = mfma16(wa1, pw1, wacc);
    int wrow = wave * 16 + qd * 4;
#pragma unroll
    for (int j = 0; j < 4; ++j)
      wlog[(wrow + j) * 17 + la] = __logf(fmaxf(wacc[j] + pb_la, 1e-6f));
    __syncthreads();                       // bar2: wlog ready
    // ---- S = QK^T/8 + wlog ----
    int m0 = t * 32;
    const ushort_t* kbase =
        Kb + (((long)(b * 1024 + m0)) << 10) + g * 64 + qd * 8;
    bf16x8 kb0 = *(const bf16x8*)(kbase + (long)la * 1024);
    bf16x8 kb1 = *(const bf16x8*)(kbase + (long)la * 1024 + 32);
    bf16x8 kb2 = *(const bf16x8*)(kbase + (long)(la + 16) * 1024);
    bf16x8 kb3 = *(const bf16x8*)(kbase + (long)(la + 16) * 1024 + 32);
    const ushort_t* vb = V2T + ((long)(b * 16 + g) << 16) + m0 + qd * 8;
    bf16x8 v0 = *(const bf16x8*)(vb + (long)la * 1024);
    bf16x8 v1 = *(const bf16x8*)(vb + (long)(16 + la) * 1024);
    bf16x8 v2 = *(const bf16x8*)(vb + (long)(32 + la) * 1024);
    bf16x8 v3 = *(const bf16x8*)(vb + (long)(48 + la) * 1024);
    f32x4 s0 = {0.f, 0.f, 0.f, 0.f}, s1 = {0.f, 0.f, 0.f, 0.f};
    s0 = mfma16(aq0, kb0, s0); s0 = mfma16(aq1, kb1, s0);
    s1 = mfma16(aq0, kb2, s1); s1 = mfma16(aq1, kb3, s1);
    // ---- online softmax (rows = n, duplicated for rows>=8) ----
#pragma unroll
    for (int j = 0; j < 4; ++j) {
      int nl = (qd * 4 + j) & 7;
      float sv0 = s0[j] * 0.125f + wlog[(nl * 32 + la) * 17 + g];
      float sv1 = s1[j] * 0.125f + wlog[(nl * 32 + la + 16) * 17 + g];
      float mrow = fmaxf(sv0, sv1);
      mrow = fmaxf(mrow, __shfl_xor(mrow, 1));
      mrow = fmaxf(mrow, __shfl_xor(mrow, 2));
      mrow = fmaxf(mrow, __shfl_xor(mrow, 4));
      mrow = fmaxf(mrow, __shfl_xor(mrow, 8));
      float mn = fmaxf(m_i[j], mrow);
      float alpha = __expf(m_i[j] - mn);
      m_i[j] = mn;
      float e0v = __expf(sv0 - mn), e1v = __expf(sv1 - mn);
      float ps = e0v + e1v;
      ps += __shfl_xor(ps, 1); ps += __shfl_xor(ps, 2);
      ps += __shfl_xor(ps, 4); ps += __shfl_xor(ps, 8);
      l_i[j] = l_i[j] * alpha + ps;
      O0[j] *= alpha; O1[j] *= alpha; O2[j] *= alpha; O3[j] *= alpha;
      if (qd < 2) {                       // store P rows 0..7 (real rows)
        int row = qd * 4 + j;
        ptrb[wave][row * 32 + la] = f2bf(e0v);
        ptrb[wave][row * 32 + la + 16] = f2bf(e1v);
      }
    }
    // ---- PV: A = P^T from wave-local LDS (no block barrier needed) ----
    bf16x8 pA = *(const bf16x8*)&ptrb[wave][(la & 7) * 32 + qd * 8];
    O0 = mfma16(pA, v0, O0);
    O1 = mfma16(pA, v1, O1);
    O2 = mfma16(pA, v2, O2);
    O3 = mfma16(pA, v3, O3);
  }

  // ---- epilogue: rows 0..7 real ----
  if (qd < 2) {
    float* ob = out + (((long)(b * 1024 + n0)) << 10) + g * 64 + la;
    const float* cb = conv_b + g * 64 + la;
#pragma unroll
    for (int j = 0; j < 4; ++j) {
      int row = qd * 4 + j;
      float il = 1.0f / l_i[j];
      float* orow = ob + ((long)row << 10);
      orow[0]  = O0[j] * il + cb[0];
      orow[16] = O1[j] * il + cb[16];
      orow[32] = O2[j] * il + cb[32];
      orow[48] = O3[j] * il + cb[48];
    }
  }
}

extern "C" void kernel_launch(void* const* d_in, const int* in_sizes, int n_in,
                              void* d_out, int out_size, void* d_ws, size_t ws_size,
                              hipStream_t stream) {
  const float* roi_feat = (const float*)d_in[0];   // (2,1024,1024)
  const float* pe       = (const float*)d_in[1];   // (2,1024,1024,64)
  const float* pos_w    = (const float*)d_in[2];   // (16,64)
  const float* pos_b    = (const float*)d_in[3];   // (16)
  const float* q_w      = (const float*)d_in[4];   // (1024,1024)
  const float* q_b      = (const float*)d_in[5];   // (1024)
  const float* k_w      = (const float*)d_in[6];
  const float* k_b      = (const float*)d_in[7];
  const float* conv_w   = (const float*)d_in[8];
  const float* conv_b   = (const float*)d_in[9];
  float* out = (float*)d_out;

  char* w = (char*)d_ws;
  ushort_t* rfb   = (ushort_t*)w; w += (size_t)4 << 20;
  ushort_t* qwb   = (ushort_t*)w; w += (size_t)2 << 20;
  ushort_t* kwb   = (ushort_t*)w; w += (size_t)2 << 20;
  ushort_t* cwb   = (ushort_t*)w; w += (size_t)2 << 20;
  ushort_t* poswb = (ushort_t*)w; w += (size_t)1 << 12;
  ushort_t* Qb    = (ushort_t*)w; w += (size_t)4 << 20;
  ushort_t* Kb    = (ushort_t*)w; w += (size_t)4 << 20;
  ushort_t* V2T   = (ushort_t*)w; w += (size_t)4 << 20;

  // converts
  cvt_bf16_kernel<<<8192, 256, 0, stream>>>(roi_feat, rfb, 2097152);
  cvt_bf16_kernel<<<4096, 256, 0, stream>>>(q_w, qwb, 1048576);
  cvt_bf16_kernel<<<4096, 256, 0, stream>>>(k_w, kwb, 1048576);
  cvt_bf16_kernel<<<4096, 256, 0, stream>>>(conv_w, cwb, 1048576);
  cvt_bf16_kernel<<<4, 256, 0, stream>>>(pos_w, poswb, 1024);

  // Q = roi @ q_w^T + q_b  (bf16)
  gemm_bt<<<dim3(64, 32, 1), 256, 0, stream>>>(
      rfb, qwb, Qb, q_b, 1024, 1024, 1024, 0, 0, 0, 0, 0, 0, 1024, 1.f, 1);
  // K = roi @ k_w^T + k_b  (bf16)
  gemm_bt<<<dim3(64, 32, 1), 256, 0, stream>>>(
      rfb, kwb, Kb, k_b, 1024, 1024, 1024, 0, 0, 0, 0, 0, 0, 1024, 1.f, 1);
  // V2T[b,g][o][m] = cw_g . roi_b^T  (bf16)
  gemm_bt<<<dim3(64, 1, 32), 256, 0, stream>>>(
      cwb, rfb, V2T, (const float*)nullptr, 1024, 1024, 1024,
      0, 65536, 1048576, 0, 1048576, 65536, 1024, 1.f, 1);

  // fused S path: W-bias + QK^T + online softmax + PV
  flash_kernel<<<256, 1024, 0, stream>>>(
      pe, poswb, pos_b, Qb, Kb, V2T, conv_b, out);
}